// Round 4
// baseline (546.636 us; speedup 1.0000x reference)
//
#include <hip/hip_runtime.h>

// out[b,k,n,m] = clip(exp(-0.1*sqrt(max(|An|^2 - 2 An.Am + |Am|^2, 1e-6))), 0, 1)
// x: (8,64,512,16) fp32, msk: (8,64,512,1) fp32, out: (8,64,512,512,1) fp32 (512 MiB).
//
// v5: kill the end-of-block store-drain serialization.
// Evidence: v1/v3/v4 all ~185-193 us kernel regardless of store flavor (NT vs
// plain) or tile/contiguity layout. One model fits all: at acc[8][8] register
// pressure these kernels run ~1 block/CU; each block ends with the compiler's
// mandatory s_waitcnt vmcnt(0) before s_endpgm, so every 128 KiB of output pays
// a full un-overlapped HBM drain (~5 us) with the CU idle, x16 blocks ~ 185 us.
// Fix: persistent per-slice blocks -> stores stay fire-and-forget across tiles.
//  - grid = 512 blocks (one per slice) = exactly 2 blocks/CU. Each block loops
//    over its slice's 8 row-tiles (64 rows x 512 cols each); tile t+1's Gram
//    has no dependence on tile t's stores, so compute overlaps the drain inside
//    each wave. Only ONE vmcnt(0) per kernel, amortized over 1 MiB of output.
//  - lds_n eliminated: row fragments are broadcast reads from the full-slice
//    lds_m (rows are a subset of the 512 staged nodes); na_n = na_m[r0+..].
//    => a single __syncthreads in the whole kernel; main loop is barrier-free.
//  - __launch_bounds__(512,4): cap 128 VGPR -> 4 waves/SIMD -> 2 resident
//    blocks/CU (16 waves) so store-stalled waves never leave the VALU idle.
//  - asm memory clobber per tile stops LICM from hoisting the loop-invariant
//    B-fragments (16x2 f32x4 = 128 regs) out of the tile loop.
//  - NT stores (marginally best measured); every store inst = 1024 B contiguous.

typedef float f32x4 __attribute__((ext_vector_type(4)));

#define NEG_DIST_LOG2E (-0.14426950408889634f)  // -0.1 * log2(e)
#define EPS_F 1e-6f
#define LDM 516   // 512 + 4 pad

__global__ __launch_bounds__(512, 4) void node_pair_gaussian_kernel(
    const float* __restrict__ x,    // (512 slices, 512 nodes, 16 f)
    const float* __restrict__ msk,  // (512 slices, 512 nodes)
    float* __restrict__ out)        // (512 slices, 512, 512)
{
    __shared__ __align__(16) float lds_m[16][LDM];  // full slice, [f][node], masked
    __shared__ __align__(16) float na_m[512];       // |A|^2 per node

    const int tid   = threadIdx.x;       // 0..511
    const int slice = blockIdx.x;        // 0..511

    const float* xs = x   + (size_t)slice * (512 * 16);
    const float* ms = msk + (size_t)slice * 512;

    // ---- Stage full slice transposed [f][node], masked; fold in squared-norm
    //      via 4-lane shuffle reduce (4 adjacent lanes hold one node) ----
    #pragma unroll
    for (int it = 0; it < 4; ++it) {
        const int c    = tid + it * 512;          // 0..2047 = 512 nodes x 4 chunks
        const int node = c >> 2;
        const int f4   = (c & 3) * 4;
        const f32x4 v  = *(const f32x4*)(xs + (size_t)c * 4);  // coalesced
        const float mm = ms[node];
        lds_m[f4 + 0][node] = v.x * mm;
        lds_m[f4 + 1][node] = v.y * mm;
        lds_m[f4 + 2][node] = v.z * mm;
        lds_m[f4 + 3][node] = v.w * mm;
        float p = (v.x * v.x + v.y * v.y + v.z * v.z + v.w * v.w) * (mm * mm);
        p += __shfl_xor(p, 1);
        p += __shfl_xor(p, 2);
        if ((tid & 3) == 0) na_m[node] = p;
    }
    __syncthreads();   // the only barrier in the kernel

    const int lane = tid & 63;
    const int w8   = (tid >> 6) << 3;    // wave's row offset within a tile (0..56)

    // Tile-invariant column norms (lane owns cols lane*4..+3 and 256+lane*4..+3)
    const f32x4 nm0 = *(const f32x4*)&na_m[lane * 4];
    const f32x4 nm1 = *(const f32x4*)&na_m[256 + lane * 4];
    const float nm[8] = {nm0.x, nm0.y, nm0.z, nm0.w, nm1.x, nm1.y, nm1.z, nm1.w};

    float* const outs = out + (size_t)slice * (512 * 512);

    // ---- Barrier-free main loop over 8 row-tiles; stores fire-and-forget ----
    for (int r0 = 0; r0 < 512; r0 += 64) {
        asm volatile("" ::: "memory");   // block LICM of B-fragments across tiles
        const int rb = r0 + w8;          // this wave's 8 output rows: rb..rb+7

        float acc[8][8];
        #pragma unroll
        for (int i = 0; i < 8; ++i)
            #pragma unroll
            for (int j = 0; j < 8; ++j) acc[i][j] = 0.0f;

        #pragma unroll
        for (int f = 0; f < 16; ++f) {
            const f32x4 a0 = *(const f32x4*)&lds_m[f][rb];          // broadcast
            const f32x4 a1 = *(const f32x4*)&lds_m[f][rb + 4];      // broadcast
            const f32x4 b0 = *(const f32x4*)&lds_m[f][lane * 4];        // strided
            const f32x4 b1 = *(const f32x4*)&lds_m[f][256 + lane * 4];  // strided
            const float an[8] = {a0.x, a0.y, a0.z, a0.w, a1.x, a1.y, a1.z, a1.w};
            const float am[8] = {b0.x, b0.y, b0.z, b0.w, b1.x, b1.y, b1.z, b1.w};
            #pragma unroll
            for (int i = 0; i < 8; ++i)
                #pragma unroll
                for (int j = 0; j < 8; ++j)
                    acc[i][j] = fmaf(an[i], am[j], acc[i][j]);
        }

        const f32x4 nn0 = *(const f32x4*)&na_m[rb];                 // broadcast
        const f32x4 nn1 = *(const f32x4*)&na_m[rb + 4];
        const float nn[8] = {nn0.x, nn0.y, nn0.z, nn0.w, nn1.x, nn1.y, nn1.z, nn1.w};

        #pragma unroll
        for (int i = 0; i < 8; ++i) {
            float r[8];
            #pragma unroll
            for (int j = 0; j < 8; ++j) {
                float s = fmaf(-2.0f, acc[i][j], nn[i] + nm[j]);
                s = fmaxf(s, EPS_F);
                const float d = __builtin_amdgcn_sqrtf(s);
                const float e = __builtin_amdgcn_exp2f(d * NEG_DIST_LOG2E);
                r[j] = fminf(e, 1.0f);   // CLIP_LOW=0 implied: e > 0 always
            }
            f32x4 w0 = {r[0], r[1], r[2], r[3]};
            f32x4 w1 = {r[4], r[5], r[6], r[7]};
            float* rowp = outs + (size_t)(rb + i) * 512;
            __builtin_nontemporal_store(w0, (f32x4*)(rowp + lane * 4));
            __builtin_nontemporal_store(w1, (f32x4*)(rowp + 256 + lane * 4));
        }
    }
}

extern "C" void kernel_launch(void* const* d_in, const int* in_sizes, int n_in,
                              void* d_out, int out_size, void* d_ws, size_t ws_size,
                              hipStream_t stream) {
    const float* x   = (const float*)d_in[0];   // (8,64,512,16) fp32
    const float* msk = (const float*)d_in[1];   // (8,64,512,1)  fp32
    float* out = (float*)d_out;                 // (8,64,512,512,1) fp32

    dim3 grid(512);   // one block per (b,k) slice; exactly 2 blocks per CU
    node_pair_gaussian_kernel<<<grid, 512, 0, stream>>>(x, msk, out);
}

// Round 6
// 544.445 us; speedup vs baseline: 1.0040x; 1.0040x over previous
//
#include <hip/hip_runtime.h>

// out[b,k,n,m] = clip(exp(-0.1*sqrt(max(|An|^2 - 2 An.Am + |Am|^2, 1e-6))), 0, 1)
// x: (8,64,512,16) fp32, msk: (8,64,512,1) fp32, out: (8,64,512,512,1) fp32 (512 MiB).
//
// v6 (resubmit — R5 was an infra failure, not a kernel result).
// MFMA Gram with FULL-CACHE-LINE stores (the decisive probe).
// Ledger: v1/v3/v4/v5 all ~185-205 us kernel vs 85 us write floor; only store
// SEGMENT SIZE ever mattered (v2's 64 B segments: +70 us). Two surviving models:
// (A) resource-sum-bound with zero phase overlap (FMA 27 + LDS 20 + epilogue 22
// + stage 4 + writes 85 ~= 185); (B) mixed-kernel write path ~2.9 TB/s ceiling.
// This kernel removes ~45 us of (A)'s compute via the matrix pipe while keeping
// the write pattern at fill granularity:
//  - v_mfma_f32_32x32x16_f16: K=16 = feature count, one MFMA per 32x32 tile.
//    D-layout col=lane&31, row=(reg&3)+8*(reg>>2)+4*(lane>>5)  [measured,
//    dtype-independent] -> a plain global_store_dword covers TWO FULL 128 B
//    lines per instruction (each 32-lane half = 32 consecutive floats of a row).
//  - Gram A.A^T: A- and B-fragments have identical lane form (node=lane&31,
//    k-half=lane>>5) -> one ds_read_b128 each from node-major f16 LDS. Any
//    k-permutation error cancels (both operands use the same map).
//  - na computed from the SAME f16-converted values (v2-proven: keeps the
//    nn+nm-2G cancellation exact; diagonal -> eps).
//  - Sequential row-tiles per wave (16 acc regs live, not 64): stores of tile
//    rt interleave with MFMA of rt+1; VGPR ~70 -> ~6-7 resident blocks/CU for
//    phase stagger across blocks.
// If this STILL lands ~185 us (headline ~525), model (B) is proven and the
// observed write ceiling is the roofline.

typedef float    f32x4  __attribute__((ext_vector_type(4)));
typedef float    f32x16 __attribute__((ext_vector_type(16)));
typedef _Float16 f16x4  __attribute__((ext_vector_type(4)));
typedef _Float16 f16x8  __attribute__((ext_vector_type(8)));

#define NEG_DIST_LOG2E (-0.14426950408889634f)  // -0.1 * log2(e)
#define EPS_F 1e-6f
#define LROW 24   // f16 row pitch (48 B): keeps f16x8 reads 16B-aligned; 4-way
                  // bank aliasing but only 5 b128 reads per wave total.

__global__ __launch_bounds__(256) void node_pair_gaussian_kernel(
    const float* __restrict__ x,    // (512 slices, 512 nodes, 16 f)
    const float* __restrict__ msk,  // (512 slices, 512 nodes)
    float* __restrict__ out)        // (512 slices, 512, 512)
{
    __shared__ __align__(16) _Float16 lds_n[128][LROW];  // row tile, node-major
    __shared__ __align__(16) _Float16 lds_m[128][LROW];  // col tile, node-major
    __shared__ __align__(16) float na_n[128];
    __shared__ __align__(16) float na_m[128];

    const int tid   = threadIdx.x;          // 0..255
    const int tile  = blockIdx.x;           // 0..15
    const int slice = blockIdx.y;           // 0..511  (= b*64 + k)
    const int n0 = (tile >> 2) << 7;        // row tile base
    const int m0 = (tile & 3) << 7;         // col tile base

    const float* xs = x   + (size_t)slice * (512 * 16);
    const float* ms = msk + (size_t)slice * 512;

    // ---- Stage both 128x16 tiles into LDS as fp16 (masked), node-major ----
    #pragma unroll
    for (int it = 0; it < 2; ++it) {
        const int task = tid + it * 256;    // 0..511 = 128 nodes x 4 f4-chunks
        const int node = task & 127;
        const int f4   = task >> 7;         // 0..3
        {
            const f32x4 v = *(const f32x4*)(xs + (size_t)(n0 + node) * 16 + f4 * 4);
            const float mm = ms[n0 + node];
            f16x4 h = { (_Float16)(v.x * mm), (_Float16)(v.y * mm),
                        (_Float16)(v.z * mm), (_Float16)(v.w * mm) };
            *(f16x4*)&lds_n[node][f4 * 4] = h;   // byte addr node*48 + f4*8
        }
        {
            const f32x4 v = *(const f32x4*)(xs + (size_t)(m0 + node) * 16 + f4 * 4);
            const float mm = ms[m0 + node];
            f16x4 h = { (_Float16)(v.x * mm), (_Float16)(v.y * mm),
                        (_Float16)(v.z * mm), (_Float16)(v.w * mm) };
            *(f16x4*)&lds_m[node][f4 * 4] = h;
        }
    }
    __syncthreads();

    // ---- Squared norms from the CONVERTED fp16 values (cancellation-exact) ----
    {
        const int node = tid & 127;
        const _Float16* p = (tid < 128) ? &lds_m[node][0] : &lds_n[node][0];
        float s = 0.0f;
        #pragma unroll
        for (int f4 = 0; f4 < 4; ++f4) {
            const f16x4 h = *(const f16x4*)&p[f4 * 4];
            const float a0 = (float)h.x, a1 = (float)h.y;
            const float a2 = (float)h.z, a3 = (float)h.w;
            s = fmaf(a0, a0, s); s = fmaf(a1, a1, s);
            s = fmaf(a2, a2, s); s = fmaf(a3, a3, s);
        }
        if (tid < 128) na_m[node] = s; else na_n[node] = s;
    }
    __syncthreads();

    // ---- MFMA Gram: wave w owns output cols m0+32w..+31, all 128 rows ----
    const int lane = tid & 63;
    const int w    = tid >> 6;      // 0..3
    const int jl   = lane & 31;     // node-within-strip = output col offset
    const int h    = lane >> 5;     // k-half selector / row nibble

    // B-fragment (col operand) is row-tile-invariant: load once.
    const f16x8 bfr = *(const f16x8*)&lds_m[w * 32 + jl][h * 8];
    const float nm  = na_m[w * 32 + jl];

    float* const outs = out + (size_t)slice * (512 * 512)
                            + (size_t)n0 * 512 + (m0 + w * 32);

    #pragma unroll
    for (int rt = 0; rt < 4; ++rt) {
        const f16x8 afr = *(const f16x8*)&lds_n[rt * 32 + jl][h * 8];
        const f32x16 z = {0.0f,0.0f,0.0f,0.0f, 0.0f,0.0f,0.0f,0.0f,
                          0.0f,0.0f,0.0f,0.0f, 0.0f,0.0f,0.0f,0.0f};
        // D[i][j] = sum_k An[n0+rt*32+i][k] * Am[m0+w*32+j][k], j = jl
        const f32x16 acc = __builtin_amdgcn_mfma_f32_32x32x16_f16(afr, bfr, z, 0, 0, 0);

        #pragma unroll
        for (int r = 0; r < 16; ++r) {
            const int row = rt * 32 + 4 * h + (r & 3) + 8 * (r >> 2);
            const float nn = na_n[row];               // 2-way broadcast read
            float s = fmaf(-2.0f, acc[r], nn + nm);
            s = fmaxf(s, EPS_F);
            const float d = __builtin_amdgcn_sqrtf(s);
            const float e = __builtin_amdgcn_exp2f(d * NEG_DIST_LOG2E);
            // Plain dword store: each 32-lane half writes one FULL 128 B line.
            outs[(size_t)row * 512 + jl] = fminf(e, 1.0f);
        }
    }
}

extern "C" void kernel_launch(void* const* d_in, const int* in_sizes, int n_in,
                              void* d_out, int out_size, void* d_ws, size_t ws_size,
                              hipStream_t stream) {
    const float* x   = (const float*)d_in[0];   // (8,64,512,16) fp32
    const float* msk = (const float*)d_in[1];   // (8,64,512,1)  fp32
    float* out = (float*)d_out;                 // (8,64,512,512,1) fp32

    dim3 grid(16, 512);   // 16 tiles of 128x128 per slice, 512 slices
    node_pair_gaussian_kernel<<<grid, 256, 0, stream>>>(x, msk, out);
}